// Round 1
// baseline (10.547 us; speedup 1.0000x reference)
//
#include <hip/hip_runtime.h>

// GANLoss: out = -sum_b [ (sum_t prob[b,t,samples[b,t]]) * (reward[b]-c_phi_z_tilde[b])
//                         + c_phi_z[b] - c_phi_z_tilde[b] ]
// B=64, T=32, V=50257. Only B*T=2048 elements of prob are needed -> pure gather.

#define GAN_B 64
#define GAN_T 32
#define GAN_V 50257
#define GAN_BT (GAN_B * GAN_T)   // 2048

__global__ __launch_bounds__(1024) void GANLoss_79319456023015_kernel(
    const float* __restrict__ prob,          // (B*T, V)
    const int*   __restrict__ samples,       // (B, T)
    const float* __restrict__ reward,        // (B,)
    const float* __restrict__ c_phi_z,       // (B,)
    const float* __restrict__ c_phi_z_tilde, // (B,)
    float* __restrict__ out)                 // scalar
{
    const int tid = threadIdx.x;

    float acc = 0.0f;

    // Gather terms: i in [0, B*T), 1024 threads x 2 iterations.
    #pragma unroll
    for (int i = tid; i < GAN_BT; i += 1024) {
        const int b = i / GAN_T;
        const int s = samples[i];
        const float p = prob[(size_t)i * GAN_V + (size_t)s];
        acc += p * (reward[b] - c_phi_z_tilde[b]);
    }

    // Per-batch constant terms (once per b).
    if (tid < GAN_B) {
        acc += c_phi_z[tid] - c_phi_z_tilde[tid];
    }

    // Wave (64-lane) butterfly reduction.
    #pragma unroll
    for (int off = 32; off > 0; off >>= 1) {
        acc += __shfl_down(acc, off, 64);
    }

    __shared__ float wsum[16];
    const int wave = tid >> 6;
    const int lane = tid & 63;
    if (lane == 0) wsum[wave] = acc;
    __syncthreads();

    if (tid == 0) {
        float s = 0.0f;
        #pragma unroll
        for (int w = 0; w < 16; ++w) s += wsum[w];
        out[0] = -s;
    }
}

extern "C" void kernel_launch(void* const* d_in, const int* in_sizes, int n_in,
                              void* d_out, int out_size, void* d_ws, size_t ws_size,
                              hipStream_t stream) {
    const float* prob          = (const float*)d_in[0];
    const int*   samples       = (const int*)d_in[1];
    const float* reward        = (const float*)d_in[2];
    const float* c_phi_z       = (const float*)d_in[3];
    const float* c_phi_z_tilde = (const float*)d_in[4];
    float* out = (float*)d_out;

    GANLoss_79319456023015_kernel<<<1, 1024, 0, stream>>>(
        prob, samples, reward, c_phi_z, c_phi_z_tilde, out);
}